// Round 4
// baseline (1149.883 us; speedup 1.0000x reference)
//
#include <hip/hip_runtime.h>

#define MAXDEG 192
#define NEG_SLOPE 0.2f
#define D 128
#define NBLK 1024   // 256 CUs x 4 blocks/CU -- structurally co-resident
#define TPB 256

__device__ __forceinline__ float bf2f(unsigned short u) {
    return __uint_as_float(((unsigned)u) << 16);
}
__device__ __forceinline__ unsigned short f2bf(float f) {
    unsigned u = __float_as_uint(f);
    return (unsigned short)((u + 0x7fffu + ((u >> 16) & 1u)) >> 16);
}
// dtype detect: adj[0,0]==1.0 guaranteed (self-loop). f32 -> 0x3F800000.
__device__ __forceinline__ int is_f32(const void* adj) {
    return ((const unsigned*)adj)[0] == 0x3F800000u;
}

// Monotonic-counter grid barrier. Valid because all NBLK blocks are
// co-resident (see launch_bounds/LDS math above).
__device__ __forceinline__ void grid_sync(int* bar, int target) {
    __syncthreads();
    __threadfence();                       // release h/asrc/cols writes
    if (threadIdx.x == 0) {
        atomicAdd(bar, 1);
        while (__hip_atomic_load(bar, __ATOMIC_RELAXED, __HIP_MEMORY_SCOPE_AGENT) < target)
            __builtin_amdgcn_s_sleep(2);
    }
    __syncthreads();
    __threadfence();                       // acquire
}

// --------------------------------------------------------------------------
// ELL compaction of one 4-row group (wave per row). Order-free.
// --------------------------------------------------------------------------
__device__ __forceinline__ void ell_group(
        int g, const void* __restrict__ adj, int N, int f32m,
        unsigned short* __restrict__ cols, int* __restrict__ deg,
        float* __restrict__ smem) {
    int* cnt = (int*)smem;  // 4 ints
    const int w = threadIdx.x >> 6, lane = threadIdx.x & 63;
    const int row = g * 4 + w;
    if (lane == 0) cnt[w] = 0;
    __syncthreads();
    unsigned short* crow = cols + (size_t)row * MAXDEG;
    if (f32m) {
        const float4* arow = (const float4*)((const float*)adj + (size_t)row * N);
        const int nv = N / 4;
        for (int v = lane; v < nv; v += 128) {
            float4 u0 = arow[v];
            float4 u1 = arow[v + 64];
            const unsigned* a0 = (const unsigned*)&u0;
            const unsigned* a1 = (const unsigned*)&u1;
            #pragma unroll
            for (int e = 0; e < 4; e++)
                if (a0[e]) { int p = atomicAdd(&cnt[w], 1); if (p < MAXDEG) crow[p] = (unsigned short)(v * 4 + e); }
            #pragma unroll
            for (int e = 0; e < 4; e++)
                if (a1[e]) { int p = atomicAdd(&cnt[w], 1); if (p < MAXDEG) crow[p] = (unsigned short)((v + 64) * 4 + e); }
        }
    } else {
        const uint4* arow = (const uint4*)((const unsigned short*)adj + (size_t)row * N);
        const int nv = N / 8;
        for (int v = lane; v < nv; v += 128) {
            uint4 u0 = arow[v];
            uint4 u1 = arow[v + 64];
            const unsigned short* s0 = (const unsigned short*)&u0;
            const unsigned short* s1 = (const unsigned short*)&u1;
            #pragma unroll
            for (int e = 0; e < 8; e++)
                if (s0[e]) { int p = atomicAdd(&cnt[w], 1); if (p < MAXDEG) crow[p] = (unsigned short)(v * 8 + e); }
            #pragma unroll
            for (int e = 0; e < 8; e++)
                if (s1[e]) { int p = atomicAdd(&cnt[w], 1); if (p < MAXDEG) crow[p] = (unsigned short)((v + 64) * 8 + e); }
        }
    }
    __syncthreads();
    if (lane == 0) deg[row] = cnt[w] < MAXDEG ? cnt[w] : MAXDEG;
}

// --------------------------------------------------------------------------
// One 32x128 tile of H = A @ W (K=128), W staged 32 rows at a time (16 KB),
// fused attention-score epilogue. smem: xs=[0,4096) f32, ws=[4096,8192) f32.
// --------------------------------------------------------------------------
__device__ __forceinline__ void gemm_tile(
        int t, const void* __restrict__ A, const void* __restrict__ W,
        int aF, int f32m, const void* __restrict__ attS, const void* __restrict__ attD,
        float* __restrict__ H, float* __restrict__ asrc, float* __restrict__ adst,
        float* __restrict__ smem) {
    float* xs = smem;
    float* ws = smem + 4096;
    const int tid = threadIdx.x;
    const size_t row0 = (size_t)t * 32;

    if (aF) {
        const float4* av = (const float4*)((const float*)A + row0 * D);
        float4* xl = (float4*)xs;
        #pragma unroll
        for (int k = 0; k < 4; k++) xl[tid + 256 * k] = av[tid + 256 * k];
    } else {
        const uint4* av = (const uint4*)((const unsigned short*)A + row0 * D);
        #pragma unroll
        for (int k = 0; k < 2; k++) {
            uint4 u = av[tid + 256 * k];
            const unsigned short* us = (const unsigned short*)&u;
            #pragma unroll
            for (int e = 0; e < 8; e++) xs[(tid + 256 * k) * 8 + e] = bf2f(us[e]);
        }
    }

    const int tx = tid & 31, ty = tid >> 5;
    const int c0 = tx * 4, r0 = ty * 4;
    float acc[4][4] = {};
    for (int p = 0; p < 4; p++) {
        __syncthreads();
        if (f32m) {
            const float4* wv = (const float4*)((const float*)W + (size_t)p * 32 * D);
            float4* wl = (float4*)ws;
            #pragma unroll
            for (int k = 0; k < 4; k++) wl[tid + 256 * k] = wv[tid + 256 * k];
        } else {
            const uint4* wv = (const uint4*)((const unsigned short*)W + (size_t)p * 32 * D);
            #pragma unroll
            for (int k = 0; k < 2; k++) {
                uint4 u = wv[tid + 256 * k];
                const unsigned short* us = (const unsigned short*)&u;
                #pragma unroll
                for (int e = 0; e < 8; e++) ws[(tid + 256 * k) * 8 + e] = bf2f(us[e]);
            }
        }
        __syncthreads();
        #pragma unroll 8
        for (int k = 0; k < 32; k++) {
            float4 wv = *(const float4*)&ws[k * D + c0];
            #pragma unroll
            for (int i = 0; i < 4; i++) {
                float xv = xs[(r0 + i) * D + p * 32 + k];
                acc[i][0] += xv * wv.x; acc[i][1] += xv * wv.y;
                acc[i][2] += xv * wv.z; acc[i][3] += xv * wv.w;
            }
        }
    }
    float* Ho = H + row0 * D;
    #pragma unroll
    for (int i = 0; i < 4; i++)
        *(float4*)&Ho[(r0 + i) * D + c0] =
            make_float4(acc[i][0], acc[i][1], acc[i][2], acc[i][3]);

    float aSv[4], aDv[4];
    #pragma unroll
    for (int j = 0; j < 4; j++) {
        aSv[j] = f32m ? ((const float*)attS)[c0 + j] : bf2f(((const unsigned short*)attS)[c0 + j]);
        aDv[j] = f32m ? ((const float*)attD)[c0 + j] : bf2f(((const unsigned short*)attD)[c0 + j]);
    }
    #pragma unroll
    for (int i = 0; i < 4; i++) {
        float s = acc[i][0] * aSv[0] + acc[i][1] * aSv[1] + acc[i][2] * aSv[2] + acc[i][3] * aSv[3];
        float d = acc[i][0] * aDv[0] + acc[i][1] * aDv[1] + acc[i][2] * aDv[2] + acc[i][3] * aDv[3];
        #pragma unroll
        for (int off = 16; off > 0; off >>= 1) {
            s += __shfl_down(s, off, 32);
            d += __shfl_down(d, off, 32);
        }
        if (tx == 0) {
            asrc[row0 + r0 + i] = s;
            adst[row0 + r0 + i] = d;
        }
    }
}

// --------------------------------------------------------------------------
// One row of softmax-aggregate (wave-local; per-wave LDS scratch).
// smem layout: scn = [0, 768) floats (4 waves x 192), sjj after it.
// --------------------------------------------------------------------------
__device__ __forceinline__ void agg_row(
        int row, const float* __restrict__ H,
        const float* __restrict__ asrc, const float* __restrict__ adst,
        const unsigned short* __restrict__ cols, const int* __restrict__ deg,
        const void* __restrict__ bias, int f32m,
        float* __restrict__ outF, void* __restrict__ outAny,
        size_t off2, int relu, float* __restrict__ smem) {
    const int w = threadIdx.x >> 6, lane = threadIdx.x & 63;
    float* scn = smem + w * MAXDEG;
    unsigned short* sjj = (unsigned short*)(smem + 4 * MAXDEG) + w * MAXDEG;
    const int d = deg[row];
    const float ai = adst[row];
    const unsigned short* crow = cols + (size_t)row * MAXDEG;

    const int s0 = lane, s1 = lane + 64, s2 = lane + 128;
    unsigned short j0 = 0, j1 = 0, j2 = 0;
    float e0 = -3e38f, e1 = -3e38f, e2 = -3e38f;
    if (s0 < d) { j0 = crow[s0]; float e = asrc[j0] + ai; e0 = (e >= 0.f) ? e : NEG_SLOPE * e; }
    if (s1 < d) { j1 = crow[s1]; float e = asrc[j1] + ai; e1 = (e >= 0.f) ? e : NEG_SLOPE * e; }
    if (s2 < d) { j2 = crow[s2]; float e = asrc[j2] + ai; e2 = (e >= 0.f) ? e : NEG_SLOPE * e; }
    float m = fmaxf(e0, fmaxf(e1, e2));
    #pragma unroll
    for (int off = 1; off < 64; off <<= 1) m = fmaxf(m, __shfl_xor(m, off));
    float p0 = (s0 < d) ? __expf(e0 - m) : 0.f;
    float p1 = (s1 < d) ? __expf(e1 - m) : 0.f;
    float p2 = (s2 < d) ? __expf(e2 - m) : 0.f;
    float l = p0 + p1 + p2;
    #pragma unroll
    for (int off = 1; off < 64; off <<= 1) l += __shfl_xor(l, off);
    const float invl = 1.f / l;
    scn[s0] = p0 * invl; sjj[s0] = j0;
    scn[s1] = p1 * invl; sjj[s1] = j1;
    scn[s2] = p2 * invl; sjj[s2] = j2;
    // same-wave LDS RAW: no block barrier needed

    const float2* H2 = (const float2*)H;
    float2 a0 = make_float2(0.f, 0.f), a1 = a0, a2 = a0, a3 = a0;
    int k = 0;
    for (; k + 3 < d; k += 4) {
        const int ja = sjj[k], jb = sjj[k + 1], jc = sjj[k + 2], jd = sjj[k + 3];
        const float wa = scn[k], wb = scn[k + 1], wc = scn[k + 2], wd = scn[k + 3];
        const float2 va = H2[(size_t)ja * 64 + lane];
        const float2 vb = H2[(size_t)jb * 64 + lane];
        const float2 vc = H2[(size_t)jc * 64 + lane];
        const float2 vd = H2[(size_t)jd * 64 + lane];
        a0.x += wa * va.x; a0.y += wa * va.y;
        a1.x += wb * vb.x; a1.y += wb * vb.y;
        a2.x += wc * vc.x; a2.y += wc * vc.y;
        a3.x += wd * vd.x; a3.y += wd * vd.y;
    }
    for (; k < d; k++) {
        const int j = sjj[k];
        const float wk = scn[k];
        const float2 v = H2[(size_t)j * 64 + lane];
        a0.x += wk * v.x; a0.y += wk * v.y;
    }
    float vx = a0.x + a1.x + a2.x + a3.x;
    float vy = a0.y + a1.y + a2.y + a3.y;

    const int c0 = lane * 2;
    const float bx = f32m ? ((const float*)bias)[c0]     : bf2f(((const unsigned short*)bias)[c0]);
    const float by = f32m ? ((const float*)bias)[c0 + 1] : bf2f(((const unsigned short*)bias)[c0 + 1]);
    vx += bx; vy += by;
    if (relu) { vx = fmaxf(vx, 0.f); vy = fmaxf(vy, 0.f); }
    if (outF) ((float2*)outF)[(size_t)row * 64 + lane] = make_float2(vx, vy);
    if (f32m) {
        ((float2*)outAny)[off2 + (size_t)row * 64 + lane] = make_float2(vx, vy);
    } else {
        unsigned packed = (unsigned)f2bf(vx) | ((unsigned)f2bf(vy) << 16);
        ((unsigned*)outAny)[off2 + (size_t)row * 64 + lane] = packed;
    }
}

// --------------------------------------------------------------------------
__global__ __launch_bounds__(TPB, 4) void gat_mega(
        const void* __restrict__ x, const void* __restrict__ adj,
        const void* __restrict__ W0, const void* __restrict__ aS0,
        const void* __restrict__ aD0, const void* __restrict__ b0,
        const void* __restrict__ W1, const void* __restrict__ aS1,
        const void* __restrict__ aD1, const void* __restrict__ b1,
        void* __restrict__ out, int N,
        int* __restrict__ bar, int* __restrict__ qhead,
        int* __restrict__ deg, unsigned short* __restrict__ cols,
        float* __restrict__ h, float* __restrict__ out0,
        float* __restrict__ asrc, float* __restrict__ adst) {
    __shared__ float smem[8192]; // 32 KB
    __shared__ int sgrp;
    const int bid = blockIdx.x, tid = threadIdx.x;
    const int f32m = is_f32(adj);
    const int GT = N / 32;   // gemm tiles (256)
    const int NG = N / 4;    // ell 4-row groups (2048)

    // ---- P0: gemm layer0 (first GT blocks) + work-queued ELL compaction
    if (bid < GT)
        gemm_tile(bid, x, W0, f32m, f32m, aS0, aD0, h, asrc, adst, smem);
    __syncthreads();
    for (;;) {
        if (tid == 0) sgrp = atomicAdd(qhead, 1);
        __syncthreads();
        const int g = sgrp;
        __syncthreads();
        if (g >= NG) break;
        ell_group(g, adj, N, f32m, cols, deg, smem);
    }
    grid_sync(bar, NBLK);

    // ---- P1: aggregate layer0 (relu, keep f32 copy for layer1)
    {
        const int gw = bid * 4 + (tid >> 6);
        for (int r = gw; r < N; r += NBLK * 4)
            agg_row(r, h, asrc, adst, cols, deg, b0, f32m, out0, out, 0, 1, smem);
    }
    grid_sync(bar, 2 * NBLK);

    // ---- P2: gemm layer1 (A = f32 out0)
    if (bid < GT)
        gemm_tile(bid, out0, W1, 1, f32m, aS1, aD1, h, asrc, adst, smem);
    grid_sync(bar, 3 * NBLK);

    // ---- P3: aggregate layer1 (final output)
    {
        const int gw = bid * 4 + (tid >> 6);
        for (int r = gw; r < N; r += NBLK * 4)
            agg_row(r, h, asrc, adst, cols, deg, b1, f32m, nullptr, out,
                    (size_t)N * (D / 2), 0, smem);
    }
}

// --------------------------------------------------------------------------
extern "C" void kernel_launch(void* const* d_in, const int* in_sizes, int n_in,
                              void* d_out, int out_size, void* d_ws, size_t ws_size,
                              hipStream_t stream) {
    const int N = in_sizes[0] / D; // 8192

    char* w = (char*)d_ws;
    int* bar             = (int*)w;            // [0,64): barrier counter
    int* qhead           = (int*)(w + 64);     // [64,128): ell work queue
    w += 256;
    int* deg             = (int*)w;            w += (size_t)N * sizeof(int);
    unsigned short* cols = (unsigned short*)w; w += (size_t)N * MAXDEG * sizeof(unsigned short);
    float* h             = (float*)w;          w += (size_t)N * D * sizeof(float);
    float* out0          = (float*)w;          w += (size_t)N * D * sizeof(float);
    float* asrc          = (float*)w;          w += (size_t)N * sizeof(float);
    float* adst          = (float*)w;

    hipMemsetAsync(d_ws, 0, 256, stream); // zero barrier + queue (ws is poisoned)

    gat_mega<<<NBLK, TPB, 0, stream>>>(
        d_in[0], d_in[1], d_in[2], d_in[3], d_in[4], d_in[5],
        d_in[6], d_in[7], d_in[8], d_in[9],
        d_out, N, bar, qhead, deg, cols, h, out0, asrc, adst);
}

// Round 5
// 448.820 us; speedup vs baseline: 2.5620x; 2.5620x over previous
//
#include <hip/hip_runtime.h>

#define MAXDEG 192
#define NEG_SLOPE 0.2f
#define D 128

__device__ __forceinline__ float bf2f(unsigned short u) {
    return __uint_as_float(((unsigned)u) << 16);
}
__device__ __forceinline__ unsigned short f2bf(float f) {
    unsigned u = __float_as_uint(f);
    return (unsigned short)((u + 0x7fffu + ((u >> 16) & 1u)) >> 16);
}
// dtype detect: adj[0,0]==1.0 guaranteed (self-loop). f32 -> 0x3F800000.
__device__ __forceinline__ int is_f32(const void* adj) {
    return ((const unsigned*)adj)[0] == 0x3F800000u;
}

// --------------------------------------------------------------------------
// ELL compaction of one 4-row group (wave per row). Order-free.
// --------------------------------------------------------------------------
__device__ __forceinline__ void ell_group(
        int g, const void* __restrict__ adj, int N, int f32m,
        unsigned short* __restrict__ cols, int* __restrict__ deg,
        int* __restrict__ cnt /* 4 ints LDS */) {
    const int w = threadIdx.x >> 6, lane = threadIdx.x & 63;
    const int row = g * 4 + w;
    if (lane == 0) cnt[w] = 0;
    __syncthreads();
    unsigned short* crow = cols + (size_t)row * MAXDEG;
    if (f32m) {
        const float4* arow = (const float4*)((const float*)adj + (size_t)row * N);
        const int nv = N / 4;
        for (int v = lane; v < nv; v += 128) {
            float4 u0 = arow[v];
            float4 u1 = arow[v + 64];
            const unsigned* a0 = (const unsigned*)&u0;
            const unsigned* a1 = (const unsigned*)&u1;
            #pragma unroll
            for (int e = 0; e < 4; e++)
                if (a0[e]) { int p = atomicAdd(&cnt[w], 1); if (p < MAXDEG) crow[p] = (unsigned short)(v * 4 + e); }
            #pragma unroll
            for (int e = 0; e < 4; e++)
                if (a1[e]) { int p = atomicAdd(&cnt[w], 1); if (p < MAXDEG) crow[p] = (unsigned short)((v + 64) * 4 + e); }
        }
    } else {
        const uint4* arow = (const uint4*)((const unsigned short*)adj + (size_t)row * N);
        const int nv = N / 8;
        for (int v = lane; v < nv; v += 128) {
            uint4 u0 = arow[v];
            uint4 u1 = arow[v + 64];
            const unsigned short* s0 = (const unsigned short*)&u0;
            const unsigned short* s1 = (const unsigned short*)&u1;
            #pragma unroll
            for (int e = 0; e < 8; e++)
                if (s0[e]) { int p = atomicAdd(&cnt[w], 1); if (p < MAXDEG) crow[p] = (unsigned short)(v * 8 + e); }
            #pragma unroll
            for (int e = 0; e < 8; e++)
                if (s1[e]) { int p = atomicAdd(&cnt[w], 1); if (p < MAXDEG) crow[p] = (unsigned short)((v + 64) * 8 + e); }
        }
    }
    __syncthreads();
    if (lane == 0) deg[row] = cnt[w] < MAXDEG ? cnt[w] : MAXDEG;
}

// --------------------------------------------------------------------------
// One 32x128 tile of H = A @ W (K=128), W staged 32 rows at a time,
// fused attention-score epilogue. smem: xs=[0,4096) f32, ws=[4096,8192).
// --------------------------------------------------------------------------
__device__ __forceinline__ void gemm_tile(
        int t, const void* __restrict__ A, const void* __restrict__ W,
        int aF, int f32m, const void* __restrict__ attS, const void* __restrict__ attD,
        float* __restrict__ H, float* __restrict__ asrc, float* __restrict__ adst,
        float* __restrict__ smem) {
    float* xs = smem;
    float* ws = smem + 4096;
    const int tid = threadIdx.x;
    const size_t row0 = (size_t)t * 32;

    if (aF) {
        const float4* av = (const float4*)((const float*)A + row0 * D);
        float4* xl = (float4*)xs;
        #pragma unroll
        for (int k = 0; k < 4; k++) xl[tid + 256 * k] = av[tid + 256 * k];
    } else {
        const uint4* av = (const uint4*)((const unsigned short*)A + row0 * D);
        #pragma unroll
        for (int k = 0; k < 2; k++) {
            uint4 u = av[tid + 256 * k];
            const unsigned short* us = (const unsigned short*)&u;
            #pragma unroll
            for (int e = 0; e < 8; e++) xs[(tid + 256 * k) * 8 + e] = bf2f(us[e]);
        }
    }

    const int tx = tid & 31, ty = tid >> 5;
    const int c0 = tx * 4, r0 = ty * 4;
    float acc[4][4] = {};
    for (int p = 0; p < 4; p++) {
        __syncthreads();
        if (f32m) {
            const float4* wv = (const float4*)((const float*)W + (size_t)p * 32 * D);
            float4* wl = (float4*)ws;
            #pragma unroll
            for (int k = 0; k < 4; k++) wl[tid + 256 * k] = wv[tid + 256 * k];
        } else {
            const uint4* wv = (const uint4*)((const unsigned short*)W + (size_t)p * 32 * D);
            #pragma unroll
            for (int k = 0; k < 2; k++) {
                uint4 u = wv[tid + 256 * k];
                const unsigned short* us = (const unsigned short*)&u;
                #pragma unroll
                for (int e = 0; e < 8; e++) ws[(tid + 256 * k) * 8 + e] = bf2f(us[e]);
            }
        }
        __syncthreads();
        #pragma unroll 8
        for (int k = 0; k < 32; k++) {
            float4 wv = *(const float4*)&ws[k * D + c0];
            #pragma unroll
            for (int i = 0; i < 4; i++) {
                float xv = xs[(r0 + i) * D + p * 32 + k];
                acc[i][0] += xv * wv.x; acc[i][1] += xv * wv.y;
                acc[i][2] += xv * wv.z; acc[i][3] += xv * wv.w;
            }
        }
    }
    float* Ho = H + row0 * D;
    #pragma unroll
    for (int i = 0; i < 4; i++)
        *(float4*)&Ho[(r0 + i) * D + c0] =
            make_float4(acc[i][0], acc[i][1], acc[i][2], acc[i][3]);

    float aSv[4], aDv[4];
    #pragma unroll
    for (int j = 0; j < 4; j++) {
        aSv[j] = f32m ? ((const float*)attS)[c0 + j] : bf2f(((const unsigned short*)attS)[c0 + j]);
        aDv[j] = f32m ? ((const float*)attD)[c0 + j] : bf2f(((const unsigned short*)attD)[c0 + j]);
    }
    #pragma unroll
    for (int i = 0; i < 4; i++) {
        float s = acc[i][0] * aSv[0] + acc[i][1] * aSv[1] + acc[i][2] * aSv[2] + acc[i][3] * aSv[3];
        float d = acc[i][0] * aDv[0] + acc[i][1] * aDv[1] + acc[i][2] * aDv[2] + acc[i][3] * aDv[3];
        #pragma unroll
        for (int off = 16; off > 0; off >>= 1) {
            s += __shfl_down(s, off, 32);
            d += __shfl_down(d, off, 32);
        }
        if (tx == 0) {
            asrc[row0 + r0 + i] = s;
            adst[row0 + r0 + i] = d;
        }
    }
}

// --------------------------------------------------------------------------
// K1: independent work fused -- blocks [0,GT) do gemm layer0, blocks
// [GT, GT+N/4) do ELL compaction. No inter-phase dependency.
// --------------------------------------------------------------------------
__global__ __launch_bounds__(256) void ell_gemm0(
        const void* __restrict__ x, const void* __restrict__ adj,
        const void* __restrict__ W0, const void* __restrict__ aS0,
        const void* __restrict__ aD0, int N,
        unsigned short* __restrict__ cols, int* __restrict__ deg,
        float* __restrict__ h, float* __restrict__ asrc, float* __restrict__ adst) {
    __shared__ float smem[8192]; // 32 KB (gemm); ELL uses first 4 ints
    const int bid = blockIdx.x;
    const int f32m = is_f32(adj);
    const int GT = N / 32;
    if (bid < GT)
        gemm_tile(bid, x, W0, f32m, f32m, aS0, aD0, h, asrc, adst, smem);
    else
        ell_group(bid - GT, adj, N, f32m, cols, deg, (int*)smem);
}

// --------------------------------------------------------------------------
// Aggregate kernel: 4 rows per block (wave per row), softmax intra-wave,
// gather with 8 independent float2 chains.
// --------------------------------------------------------------------------
__global__ __launch_bounds__(256) void aggregate(
        const float* __restrict__ H,
        const float* __restrict__ asrc, const float* __restrict__ adst,
        const unsigned short* __restrict__ cols, const int* __restrict__ deg,
        const void* __restrict__ bias, const void* __restrict__ adjFlag,
        float* __restrict__ outF, void* __restrict__ outAny,
        size_t off2, int relu) {
    __shared__ float scnA[4 * MAXDEG];
    __shared__ unsigned short sjjA[4 * MAXDEG];
    const int w = threadIdx.x >> 6, lane = threadIdx.x & 63;
    const int row = blockIdx.x * 4 + w;
    float* scn = scnA + w * MAXDEG;
    unsigned short* sjj = sjjA + w * MAXDEG;
    const int d = deg[row];
    const float ai = adst[row];
    const unsigned short* crow = cols + (size_t)row * MAXDEG;

    // softmax weights (3 slots per lane, wave-local reductions)
    const int s0 = lane, s1 = lane + 64, s2 = lane + 128;
    unsigned short j0 = 0, j1 = 0, j2 = 0;
    float e0 = -3e38f, e1 = -3e38f, e2 = -3e38f;
    if (s0 < d) { j0 = crow[s0]; float e = asrc[j0] + ai; e0 = (e >= 0.f) ? e : NEG_SLOPE * e; }
    if (s1 < d) { j1 = crow[s1]; float e = asrc[j1] + ai; e1 = (e >= 0.f) ? e : NEG_SLOPE * e; }
    if (s2 < d) { j2 = crow[s2]; float e = asrc[j2] + ai; e2 = (e >= 0.f) ? e : NEG_SLOPE * e; }
    float m = fmaxf(e0, fmaxf(e1, e2));
    #pragma unroll
    for (int off = 1; off < 64; off <<= 1) m = fmaxf(m, __shfl_xor(m, off));
    float p0 = (s0 < d) ? __expf(e0 - m) : 0.f;
    float p1 = (s1 < d) ? __expf(e1 - m) : 0.f;
    float p2 = (s2 < d) ? __expf(e2 - m) : 0.f;
    float l = p0 + p1 + p2;
    #pragma unroll
    for (int off = 1; off < 64; off <<= 1) l += __shfl_xor(l, off);
    const float invl = 1.f / l;
    scn[s0] = p0 * invl; sjj[s0] = j0;
    scn[s1] = p1 * invl; sjj[s1] = j1;
    scn[s2] = p2 * invl; sjj[s2] = j2;
    // same-wave LDS RAW: no block barrier needed

    // gather: 8 independent chains, 8 x 512B in flight per wave
    const float2* H2 = (const float2*)H;
    float2 acc[8];
    #pragma unroll
    for (int u = 0; u < 8; u++) acc[u] = make_float2(0.f, 0.f);
    int k = 0;
    for (; k + 7 < d; k += 8) {
        int jj[8]; float ww[8]; float2 vv[8];
        #pragma unroll
        for (int u = 0; u < 8; u++) { jj[u] = sjj[k + u]; ww[u] = scn[k + u]; }
        #pragma unroll
        for (int u = 0; u < 8; u++) vv[u] = H2[(size_t)jj[u] * 64 + lane];
        #pragma unroll
        for (int u = 0; u < 8; u++) { acc[u].x += ww[u] * vv[u].x; acc[u].y += ww[u] * vv[u].y; }
    }
    for (; k < d; k++) {
        const int j = sjj[k];
        const float wk = scn[k];
        const float2 v = H2[(size_t)j * 64 + lane];
        acc[0].x += wk * v.x; acc[0].y += wk * v.y;
    }
    #pragma unroll
    for (int u = 1; u < 8; u++) { acc[0].x += acc[u].x; acc[0].y += acc[u].y; }
    float vx = acc[0].x, vy = acc[0].y;

    const int f32m = is_f32(adjFlag);
    const int c0 = lane * 2;
    const float bx = f32m ? ((const float*)bias)[c0]     : bf2f(((const unsigned short*)bias)[c0]);
    const float by = f32m ? ((const float*)bias)[c0 + 1] : bf2f(((const unsigned short*)bias)[c0 + 1]);
    vx += bx; vy += by;
    if (relu) { vx = fmaxf(vx, 0.f); vy = fmaxf(vy, 0.f); }
    if (outF) ((float2*)outF)[(size_t)row * 64 + lane] = make_float2(vx, vy);
    if (f32m) {
        ((float2*)outAny)[off2 + (size_t)row * 64 + lane] = make_float2(vx, vy);
    } else {
        unsigned packed = (unsigned)f2bf(vx) | ((unsigned)f2bf(vy) << 16);
        ((unsigned*)outAny)[off2 + (size_t)row * 64 + lane] = packed;
    }
}

// --------------------------------------------------------------------------
// K3: gemm layer1 only (A = f32 out0).
// --------------------------------------------------------------------------
__global__ __launch_bounds__(256) void gemm1(
        const float* __restrict__ A, const void* __restrict__ W1,
        const void* __restrict__ aS1, const void* __restrict__ aD1,
        const void* __restrict__ adjFlag,
        float* __restrict__ h, float* __restrict__ asrc, float* __restrict__ adst) {
    __shared__ float smem[8192];
    const int f32m = is_f32(adjFlag);
    gemm_tile(blockIdx.x, A, W1, 1, f32m, aS1, aD1, h, asrc, adst, smem);
}

// --------------------------------------------------------------------------
extern "C" void kernel_launch(void* const* d_in, const int* in_sizes, int n_in,
                              void* d_out, int out_size, void* d_ws, size_t ws_size,
                              hipStream_t stream) {
    const int N = in_sizes[0] / D; // 8192

    char* w = (char*)d_ws;
    int* deg             = (int*)w;            w += (size_t)N * sizeof(int);
    unsigned short* cols = (unsigned short*)w; w += (size_t)N * MAXDEG * sizeof(unsigned short);
    float* h             = (float*)w;          w += (size_t)N * D * sizeof(float);
    float* out0          = (float*)w;          w += (size_t)N * D * sizeof(float);
    float* asrc          = (float*)w;          w += (size_t)N * sizeof(float);
    float* adst          = (float*)w;

    const void* adj = d_in[1];

    // K1: ELL build + gemm layer0 (independent; fused, no barrier)
    ell_gemm0<<<N / 32 + N / 4, 256, 0, stream>>>(
        d_in[0], adj, d_in[2], d_in[3], d_in[4], N, cols, deg, h, asrc, adst);

    // K2: aggregate layer0 (relu; f32 copy for layer1 + bf16/f32 output 0)
    aggregate<<<N / 4, 256, 0, stream>>>(h, asrc, adst, cols, deg, d_in[5], adj,
                                         out0, d_out, 0, 1);

    // K3: gemm layer1
    gemm1<<<N / 32, 256, 0, stream>>>(out0, d_in[6], d_in[7], d_in[8], adj,
                                      h, asrc, adst);

    // K4: aggregate layer1 (final output)
    aggregate<<<N / 4, 256, 0, stream>>>(h, asrc, adst, cols, deg, d_in[9], adj,
                                         nullptr, d_out, (size_t)N * (D / 2), 0);
}

// Round 6
// 419.069 us; speedup vs baseline: 2.7439x; 1.0710x over previous
//
#include <hip/hip_runtime.h>

#define MAXDEG 192
#define NEG_SLOPE 0.2f
#define D 128

__device__ __forceinline__ float bf2f(unsigned short u) {
    return __uint_as_float(((unsigned)u) << 16);
}
__device__ __forceinline__ unsigned short f2bf(float f) {
    unsigned u = __float_as_uint(f);
    return (unsigned short)((u + 0x7fffu + ((u >> 16) & 1u)) >> 16);
}
__device__ __forceinline__ unsigned pack2bf(float x, float y) {
    return (unsigned)f2bf(x) | ((unsigned)f2bf(y) << 16);
}
// dtype detect: adj[0,0]==1.0 guaranteed (self-loop). f32 -> 0x3F800000.
__device__ __forceinline__ int is_f32(const void* adj) {
    return ((const unsigned*)adj)[0] == 0x3F800000u;
}

// --------------------------------------------------------------------------
// ELL compaction of one 4-row group (wave per row). Order-free.
// --------------------------------------------------------------------------
__device__ __forceinline__ void ell_group(
        int g, const void* __restrict__ adj, int N, int f32m,
        unsigned short* __restrict__ cols, int* __restrict__ deg,
        int* __restrict__ cnt /* 4 ints LDS */) {
    const int w = threadIdx.x >> 6, lane = threadIdx.x & 63;
    const int row = g * 4 + w;
    if (lane == 0) cnt[w] = 0;
    __syncthreads();
    unsigned short* crow = cols + (size_t)row * MAXDEG;
    if (f32m) {
        const float4* arow = (const float4*)((const float*)adj + (size_t)row * N);
        const int nv = N / 4;
        for (int v = lane; v < nv; v += 128) {
            float4 u0 = arow[v];
            float4 u1 = arow[v + 64];
            const unsigned* a0 = (const unsigned*)&u0;
            const unsigned* a1 = (const unsigned*)&u1;
            #pragma unroll
            for (int e = 0; e < 4; e++)
                if (a0[e]) { int p = atomicAdd(&cnt[w], 1); if (p < MAXDEG) crow[p] = (unsigned short)(v * 4 + e); }
            #pragma unroll
            for (int e = 0; e < 4; e++)
                if (a1[e]) { int p = atomicAdd(&cnt[w], 1); if (p < MAXDEG) crow[p] = (unsigned short)((v + 64) * 4 + e); }
        }
    } else {
        const uint4* arow = (const uint4*)((const unsigned short*)adj + (size_t)row * N);
        const int nv = N / 8;
        for (int v = lane; v < nv; v += 128) {
            uint4 u0 = arow[v];
            uint4 u1 = arow[v + 64];
            const unsigned short* s0 = (const unsigned short*)&u0;
            const unsigned short* s1 = (const unsigned short*)&u1;
            #pragma unroll
            for (int e = 0; e < 8; e++)
                if (s0[e]) { int p = atomicAdd(&cnt[w], 1); if (p < MAXDEG) crow[p] = (unsigned short)(v * 8 + e); }
            #pragma unroll
            for (int e = 0; e < 8; e++)
                if (s1[e]) { int p = atomicAdd(&cnt[w], 1); if (p < MAXDEG) crow[p] = (unsigned short)((v + 64) * 8 + e); }
        }
    }
    __syncthreads();
    if (lane == 0) deg[row] = cnt[w] < MAXDEG ? cnt[w] : MAXDEG;
}

// --------------------------------------------------------------------------
// 32x128 tile of H = A @ W (K=128), H written as bf16. Fused score epilogue
// (scores from f32 accumulators, so bf16 H costs no score accuracy).
// smem: xs=[0,4096) f32, ws=[4096,8192) f32.
// --------------------------------------------------------------------------
__device__ __forceinline__ void gemm_tile32(
        int t, const void* __restrict__ A, const void* __restrict__ W,
        int aF, int f32m, const void* __restrict__ attS, const void* __restrict__ attD,
        unsigned short* __restrict__ Hb, float* __restrict__ asrc, float* __restrict__ adst,
        float* __restrict__ smem) {
    float* xs = smem;
    float* ws = smem + 4096;
    const int tid = threadIdx.x;
    const size_t row0 = (size_t)t * 32;

    if (aF) {
        const float4* av = (const float4*)((const float*)A + row0 * D);
        float4* xl = (float4*)xs;
        #pragma unroll
        for (int k = 0; k < 4; k++) xl[tid + 256 * k] = av[tid + 256 * k];
    } else {
        const uint4* av = (const uint4*)((const unsigned short*)A + row0 * D);
        #pragma unroll
        for (int k = 0; k < 2; k++) {
            uint4 u = av[tid + 256 * k];
            const unsigned short* us = (const unsigned short*)&u;
            #pragma unroll
            for (int e = 0; e < 8; e++) xs[(tid + 256 * k) * 8 + e] = bf2f(us[e]);
        }
    }

    const int tx = tid & 31, ty = tid >> 5;
    const int c0 = tx * 4, r0 = ty * 4;
    float acc[4][4] = {};
    for (int p = 0; p < 4; p++) {
        __syncthreads();
        if (f32m) {
            const float4* wv = (const float4*)((const float*)W + (size_t)p * 32 * D);
            float4* wl = (float4*)ws;
            #pragma unroll
            for (int k = 0; k < 4; k++) wl[tid + 256 * k] = wv[tid + 256 * k];
        } else {
            const uint4* wv = (const uint4*)((const unsigned short*)W + (size_t)p * 32 * D);
            #pragma unroll
            for (int k = 0; k < 2; k++) {
                uint4 u = wv[tid + 256 * k];
                const unsigned short* us = (const unsigned short*)&u;
                #pragma unroll
                for (int e = 0; e < 8; e++) ws[(tid + 256 * k) * 8 + e] = bf2f(us[e]);
            }
        }
        __syncthreads();
        #pragma unroll 8
        for (int k = 0; k < 32; k++) {
            float4 wv = *(const float4*)&ws[k * D + c0];
            #pragma unroll
            for (int i = 0; i < 4; i++) {
                float xv = xs[(r0 + i) * D + p * 32 + k];
                acc[i][0] += xv * wv.x; acc[i][1] += xv * wv.y;
                acc[i][2] += xv * wv.z; acc[i][3] += xv * wv.w;
            }
        }
    }
    // bf16 H store (8 B per thread-row)
    #pragma unroll
    for (int i = 0; i < 4; i++) {
        ushort4 hv;
        hv.x = f2bf(acc[i][0]); hv.y = f2bf(acc[i][1]);
        hv.z = f2bf(acc[i][2]); hv.w = f2bf(acc[i][3]);
        *(ushort4*)&Hb[(row0 + r0 + i) * D + c0] = hv;
    }

    float aSv[4], aDv[4];
    #pragma unroll
    for (int j = 0; j < 4; j++) {
        aSv[j] = f32m ? ((const float*)attS)[c0 + j] : bf2f(((const unsigned short*)attS)[c0 + j]);
        aDv[j] = f32m ? ((const float*)attD)[c0 + j] : bf2f(((const unsigned short*)attD)[c0 + j]);
    }
    #pragma unroll
    for (int i = 0; i < 4; i++) {
        float s = acc[i][0] * aSv[0] + acc[i][1] * aSv[1] + acc[i][2] * aSv[2] + acc[i][3] * aSv[3];
        float d = acc[i][0] * aDv[0] + acc[i][1] * aDv[1] + acc[i][2] * aDv[2] + acc[i][3] * aDv[3];
        #pragma unroll
        for (int off = 16; off > 0; off >>= 1) {
            s += __shfl_down(s, off, 32);
            d += __shfl_down(d, off, 32);
        }
        if (tx == 0) {
            asrc[row0 + r0 + i] = s;
            adst[row0 + r0 + i] = d;
        }
    }
}

// --------------------------------------------------------------------------
// Wave-local softmax + bf16 gather for one row. Returns (vx,vy) for channels
// (2*lane, 2*lane+1), bias added, optional relu. scn/sjj are per-wave LDS.
// --------------------------------------------------------------------------
__device__ __forceinline__ float2 agg_row_bf(
        int row, const unsigned short* __restrict__ Hb,
        const float* __restrict__ asrc, float ai,
        const unsigned short* __restrict__ crow, int d,
        const void* __restrict__ bias, int f32m, int relu,
        float* __restrict__ scn, unsigned short* __restrict__ sjj, int lane) {
    const int s0 = lane, s1 = lane + 64, s2 = lane + 128;
    unsigned short j0 = 0, j1 = 0, j2 = 0;
    float e0 = -3e38f, e1 = -3e38f, e2 = -3e38f;
    if (s0 < d) { j0 = crow[s0]; float e = asrc[j0] + ai; e0 = (e >= 0.f) ? e : NEG_SLOPE * e; }
    if (s1 < d) { j1 = crow[s1]; float e = asrc[j1] + ai; e1 = (e >= 0.f) ? e : NEG_SLOPE * e; }
    if (s2 < d) { j2 = crow[s2]; float e = asrc[j2] + ai; e2 = (e >= 0.f) ? e : NEG_SLOPE * e; }
    float m = fmaxf(e0, fmaxf(e1, e2));
    #pragma unroll
    for (int off = 1; off < 64; off <<= 1) m = fmaxf(m, __shfl_xor(m, off));
    float p0 = (s0 < d) ? __expf(e0 - m) : 0.f;
    float p1 = (s1 < d) ? __expf(e1 - m) : 0.f;
    float p2 = (s2 < d) ? __expf(e2 - m) : 0.f;
    float l = p0 + p1 + p2;
    #pragma unroll
    for (int off = 1; off < 64; off <<= 1) l += __shfl_xor(l, off);
    const float invl = 1.f / l;
    scn[s0] = p0 * invl; sjj[s0] = j0;
    scn[s1] = p1 * invl; sjj[s1] = j1;
    scn[s2] = p2 * invl; sjj[s2] = j2;
    // same-wave LDS RAW: no block barrier needed

    const unsigned* H2 = (const unsigned*)Hb;  // 64 x (2 bf16) per row
    float ax[8], ay[8];
    #pragma unroll
    for (int u = 0; u < 8; u++) { ax[u] = 0.f; ay[u] = 0.f; }
    int k = 0;
    for (; k + 7 < d; k += 8) {
        int jj[8]; float ww[8]; unsigned vv[8];
        #pragma unroll
        for (int u = 0; u < 8; u++) { jj[u] = sjj[k + u]; ww[u] = scn[k + u]; }
        #pragma unroll
        for (int u = 0; u < 8; u++) vv[u] = H2[(size_t)jj[u] * 64 + lane];
        #pragma unroll
        for (int u = 0; u < 8; u++) {
            ax[u] += ww[u] * bf2f((unsigned short)(vv[u] & 0xffff));
            ay[u] += ww[u] * bf2f((unsigned short)(vv[u] >> 16));
        }
    }
    for (; k < d; k++) {
        const int j = sjj[k];
        const float wk = scn[k];
        unsigned v = H2[(size_t)j * 64 + lane];
        ax[0] += wk * bf2f((unsigned short)(v & 0xffff));
        ay[0] += wk * bf2f((unsigned short)(v >> 16));
    }
    #pragma unroll
    for (int u = 1; u < 8; u++) { ax[0] += ax[u]; ay[0] += ay[u]; }

    const int c0 = lane * 2;
    const float bx = f32m ? ((const float*)bias)[c0]     : bf2f(((const unsigned short*)bias)[c0]);
    const float by = f32m ? ((const float*)bias)[c0 + 1] : bf2f(((const unsigned short*)bias)[c0 + 1]);
    float vx = ax[0] + bx, vy = ay[0] + by;
    if (relu) { vx = fmaxf(vx, 0.f); vy = fmaxf(vy, 0.f); }
    return make_float2(vx, vy);
}

// --------------------------------------------------------------------------
// K1: blocks [0,GT) gemm layer0, blocks [GT, GT+N/4) ELL compaction.
// --------------------------------------------------------------------------
__global__ __launch_bounds__(256) void ell_gemm0(
        const void* __restrict__ x, const void* __restrict__ adj,
        const void* __restrict__ W0, const void* __restrict__ aS0,
        const void* __restrict__ aD0, int N,
        unsigned short* __restrict__ cols, int* __restrict__ deg,
        unsigned short* __restrict__ h, float* __restrict__ asrc, float* __restrict__ adst) {
    __shared__ float smem[8192]; // 32 KB (gemm); ELL uses first 4 ints
    const int bid = blockIdx.x;
    const int f32m = is_f32(adj);
    const int GT = N / 32;
    if (bid < GT)
        gemm_tile32(bid, x, W0, f32m, f32m, aS0, aD0, h, asrc, adst, smem);
    else
        ell_group(bid - GT, adj, N, f32m, cols, deg, (int*)smem);
}

// --------------------------------------------------------------------------
// K2: fused aggregate-layer0 + gemm-layer1 for 8 rows per block.
// Phase A: aggregate rows into LDS (f32) + write bf16/f32 out0 to d_out.
// Phase B: gemm those 8 rows with W1 from LDS tile, write bf16 h2 + scores.
// --------------------------------------------------------------------------
__global__ __launch_bounds__(256) void agg0_gemm1(
        const unsigned short* __restrict__ h,
        const float* __restrict__ asrc0, const float* __restrict__ adst0,
        const unsigned short* __restrict__ cols, const int* __restrict__ deg,
        const void* __restrict__ b0, const void* __restrict__ W1,
        const void* __restrict__ aS1, const void* __restrict__ aD1,
        const void* __restrict__ adjFlag, void* __restrict__ out,
        unsigned short* __restrict__ h2,
        float* __restrict__ asrc1, float* __restrict__ adst1, int N) {
    __shared__ float xs[8 * D];        // 4 KB: out0 rows f32
    __shared__ float wstage[32 * D];   // 16 KB
    __shared__ float scnA[4 * MAXDEG];
    __shared__ unsigned short sjjA[4 * MAXDEG];
    const int tid = threadIdx.x;
    const int w = tid >> 6, lane = tid & 63;
    const int f32m = is_f32(adjFlag);

    // ---- Phase A: aggregate 8 rows (2 passes x 4 waves)
    #pragma unroll
    for (int pass = 0; pass < 2; pass++) {
        const int rl = pass * 4 + w;
        const int row = blockIdx.x * 8 + rl;
        float2 v = agg_row_bf(row, h, asrc0, adst0[row],
                              cols + (size_t)row * MAXDEG, deg[row],
                              b0, f32m, 1,
                              scnA + w * MAXDEG, sjjA + w * MAXDEG, lane);
        xs[rl * D + 2 * lane]     = v.x;
        xs[rl * D + 2 * lane + 1] = v.y;
        if (f32m) ((float2*)out)[(size_t)row * 64 + lane] = v;
        else      ((unsigned*)out)[(size_t)row * 64 + lane] = pack2bf(v.x, v.y);
    }

    // ---- Phase B: gemm 8x128 @ 128x128
    const int tx = tid & 31, ty = tid >> 5;
    const int c0 = tx * 4;
    float acc[4] = {};
    for (int p = 0; p < 4; p++) {
        __syncthreads(); // phase-A xs done (p=0) / previous wstage reads done
        if (f32m) {
            const float4* wv = (const float4*)((const float*)W1 + (size_t)p * 32 * D);
            float4* wl = (float4*)wstage;
            #pragma unroll
            for (int k = 0; k < 4; k++) wl[tid + 256 * k] = wv[tid + 256 * k];
        } else {
            const uint4* wv = (const uint4*)((const unsigned short*)W1 + (size_t)p * 32 * D);
            #pragma unroll
            for (int k = 0; k < 2; k++) {
                uint4 u = wv[tid + 256 * k];
                const unsigned short* us = (const unsigned short*)&u;
                #pragma unroll
                for (int e = 0; e < 8; e++) wstage[(tid + 256 * k) * 8 + e] = bf2f(us[e]);
            }
        }
        __syncthreads();
        #pragma unroll 8
        for (int k = 0; k < 32; k++) {
            float4 wv = *(const float4*)&wstage[k * D + c0];
            float xv = xs[ty * D + p * 32 + k];
            acc[0] += xv * wv.x; acc[1] += xv * wv.y;
            acc[2] += xv * wv.z; acc[3] += xv * wv.w;
        }
    }
    const size_t row1 = (size_t)blockIdx.x * 8 + ty;
    ushort4 hv;
    hv.x = f2bf(acc[0]); hv.y = f2bf(acc[1]); hv.z = f2bf(acc[2]); hv.w = f2bf(acc[3]);
    *(ushort4*)&h2[row1 * D + c0] = hv;

    float aSv[4], aDv[4];
    #pragma unroll
    for (int j = 0; j < 4; j++) {
        aSv[j] = f32m ? ((const float*)aS1)[c0 + j] : bf2f(((const unsigned short*)aS1)[c0 + j]);
        aDv[j] = f32m ? ((const float*)aD1)[c0 + j] : bf2f(((const unsigned short*)aD1)[c0 + j]);
    }
    float s = acc[0] * aSv[0] + acc[1] * aSv[1] + acc[2] * aSv[2] + acc[3] * aSv[3];
    float d = acc[0] * aDv[0] + acc[1] * aDv[1] + acc[2] * aDv[2] + acc[3] * aDv[3];
    #pragma unroll
    for (int off = 16; off > 0; off >>= 1) {
        s += __shfl_down(s, off, 32);
        d += __shfl_down(d, off, 32);
    }
    if (tx == 0) {
        asrc1[row1] = s;
        adst1[row1] = d;
    }
}

// --------------------------------------------------------------------------
// K3: aggregate layer1 (4 rows/block), final output.
// --------------------------------------------------------------------------
__global__ __launch_bounds__(256) void aggregate1(
        const unsigned short* __restrict__ h2,
        const float* __restrict__ asrc1, const float* __restrict__ adst1,
        const unsigned short* __restrict__ cols, const int* __restrict__ deg,
        const void* __restrict__ b1, const void* __restrict__ adjFlag,
        void* __restrict__ out, int N) {
    __shared__ float scnA[4 * MAXDEG];
    __shared__ unsigned short sjjA[4 * MAXDEG];
    const int w = threadIdx.x >> 6, lane = threadIdx.x & 63;
    const int row = blockIdx.x * 4 + w;
    const int f32m = is_f32(adjFlag);
    float2 v = agg_row_bf(row, h2, asrc1, adst1[row],
                          cols + (size_t)row * MAXDEG, deg[row],
                          b1, f32m, 0,
                          scnA + w * MAXDEG, sjjA + w * MAXDEG, lane);
    const size_t off2 = (size_t)N * 64;
    if (f32m) ((float2*)out)[off2 + (size_t)row * 64 + lane] = v;
    else      ((unsigned*)out)[off2 + (size_t)row * 64 + lane] = pack2bf(v.x, v.y);
}

// --------------------------------------------------------------------------
extern "C" void kernel_launch(void* const* d_in, const int* in_sizes, int n_in,
                              void* d_out, int out_size, void* d_ws, size_t ws_size,
                              hipStream_t stream) {
    const int N = in_sizes[0] / D; // 8192

    char* w = (char*)d_ws;
    int* deg             = (int*)w;            w += (size_t)N * sizeof(int);
    unsigned short* cols = (unsigned short*)w; w += (size_t)N * MAXDEG * sizeof(unsigned short);
    unsigned short* h    = (unsigned short*)w; w += (size_t)N * D * sizeof(unsigned short);
    unsigned short* h2   = (unsigned short*)w; w += (size_t)N * D * sizeof(unsigned short);
    float* asrc0         = (float*)w;          w += (size_t)N * sizeof(float);
    float* adst0         = (float*)w;          w += (size_t)N * sizeof(float);
    float* asrc1         = (float*)w;          w += (size_t)N * sizeof(float);
    float* adst1         = (float*)w;

    const void* adj = d_in[1];

    // K1: ELL build + gemm layer0 (independent work, fused)
    ell_gemm0<<<N / 32 + N / 4, 256, 0, stream>>>(
        d_in[0], adj, d_in[2], d_in[3], d_in[4], N, cols, deg, h, asrc0, adst0);

    // K2: aggregate layer0 + gemm layer1 (per-block row ownership)
    agg0_gemm1<<<N / 8, 256, 0, stream>>>(
        h, asrc0, adst0, cols, deg, d_in[5], d_in[6], d_in[7], d_in[8],
        adj, d_out, h2, asrc1, adst1, N);

    // K3: aggregate layer1 (final output)
    aggregate1<<<N / 4, 256, 0, stream>>>(
        h2, asrc1, adst1, cols, deg, d_in[9], adj, d_out, N);
}